// Round 5
// baseline (2384.954 us; speedup 1.0000x reference)
//
#include <hip/hip_runtime.h>

// Problem constants
#define COLS_ 1453
#define NROW 1585       // KKT dim (1453 + 132)
#define NZ 128          // dominant subspace dim (= #eigs above jax-f32 pinv cutoff)
#define EGS 1536
#define NB 8192

// f64 scratch offsets in d_out g-region (dead before gemm1 writes g)
#define oV    0                        // 1585x128
#define oZ    202880                   // 1585x128
#define oT    405760                   // 384x128
#define oKZ   454912                   // 1585x128
#define oBaug 657792                   // 128x256
#define oP    690560                   // 66x66 pivot
#define oR    694916                   // 64x256
#define oJ    711300                   // 128x256
#define oF    744068                   // 128x256  (end 776836 dbl = 6.2 MB < 47.6 MB)
#define fEGT  11902976                 // float offset of Egt (u/y region; dead before gemm2)

// Hankel maps (d=4): Yf[m,c]=yd[64+m+4c], Uf[m,c]=ud[64+m+4c],
// Up[s,c]=ud[s+4c], Yp[s,c]=yd[s+4c], Yf_last4[t,c]=yd[188+t+4c]

__device__ __forceinline__ double hash01(unsigned i, unsigned j) {
  unsigned x = i * 0x9E3779B9u ^ (j * 0x85EBCA6Bu + 0xC2B2AE35u);
  x ^= x >> 16; x *= 0x7FEB352Du; x ^= x >> 15; x *= 0x846CA68Bu; x ^= x >> 16;
  return (double)(x & 0xFFFFFF) / 8388608.0 - 1.0;
}

__global__ void k_init(double* __restrict__ V) {
  int j = blockIdx.x * 16 + threadIdx.x;
  int i = blockIdx.y * 16 + threadIdx.y;
  if (i < NROW) V[i * NZ + j] = hash01(i, j);
}

// T = [Yf; Uf; Up; Yp] @ Vg   (384 x 128)
__global__ void k_T(const double* __restrict__ V, const float* __restrict__ ud,
                    const float* __restrict__ yd, double* __restrict__ T) {
  int j = blockIdx.x * 16 + threadIdx.x;   // 128
  int s = blockIdx.y * 16 + threadIdx.y;   // 384
  const float* sig; int base;
  if (s < 128)      { sig = yd; base = 64 + s; }
  else if (s < 256) { sig = ud; base = 64 + (s - 128); }
  else if (s < 320) { sig = ud; base = s - 256; }
  else              { sig = yd; base = s - 320; }
  double acc = 0.0;
#pragma unroll 4
  for (int c = 0; c < COLS_; ++c) acc += (double)sig[base + 4 * c] * V[c * NZ + j];
  T[s * NZ + j] = acc;
}

// Z_g = 2 Yf^T(wq .* T_Y) + 2 Uf^T(wr .* T_U) + A^T V_lambda
__global__ void k_Zg(const double* __restrict__ T, const double* __restrict__ V,
                     const float* __restrict__ ud, const float* __restrict__ yd,
                     const float* __restrict__ q, const float* __restrict__ r,
                     double* __restrict__ Z) {
  int j = blockIdx.x * 16 + threadIdx.x;   // 128
  int c = blockIdx.y * 16 + threadIdx.y;   // <1456
  if (c >= COLS_) return;
  double acc = 0.0;
#pragma unroll 4
  for (int m = 0; m < 128; ++m)
    acc += 2.0 * (double)q[m & 3] * (double)yd[64 + m + 4 * c] * T[m * NZ + j];
#pragma unroll 4
  for (int m = 0; m < 128; ++m)
    acc += 2.0 * (double)r[m & 3] * (double)ud[64 + m + 4 * c] * T[(128 + m) * NZ + j];
#pragma unroll 4
  for (int s = 0; s < 64; ++s)
    acc += (double)ud[s + 4 * c] * V[(COLS_ + s) * NZ + j];
#pragma unroll 4
  for (int s = 0; s < 64; ++s)
    acc += (double)yd[s + 4 * c] * V[(COLS_ + 64 + s) * NZ + j];
#pragma unroll
  for (int t = 0; t < 4; ++t)
    acc += (double)yd[188 + t + 4 * c] * V[(COLS_ + 128 + t) * NZ + j];
  Z[c * NZ + j] = acc;
}

// Z_lambda = A @ Vg (from T)
__global__ void k_Zl(const double* __restrict__ T, double* __restrict__ Z) {
  int j  = blockIdx.x * 16 + threadIdx.x;  // 128
  int rr = blockIdx.y * 16 + threadIdx.y;  // <144
  if (rr >= 132) return;
  double v;
  if (rr < 64)       v = T[(256 + rr) * NZ + j];        // Up
  else if (rr < 128) v = T[(320 + rr - 64) * NZ + j];   // Yp
  else               v = T[(124 + rr - 128) * NZ + j];  // Yf last 4
  Z[(COLS_ + rr) * NZ + j] = v;
}

// column-normalize V (one block per column)
__global__ void k_norm(double* __restrict__ V) {
  __shared__ double red[256];
  int j = blockIdx.x, tid = threadIdx.x;
  double s = 0.0;
  for (int i = tid; i < NROW; i += 256) { double v = V[i * NZ + j]; s += v * v; }
  red[tid] = s; __syncthreads();
  for (int st = 128; st > 0; st >>= 1) { if (tid < st) red[tid] += red[tid + st]; __syncthreads(); }
  double inv = rsqrt(red[0]);
  for (int i = tid; i < NROW; i += 256) V[i * NZ + j] *= inv;
}

// Baug = [ Z^T KZ | I ]  (128 x 256)
__global__ void k_B(const double* __restrict__ V, const double* __restrict__ KZ,
                    double* __restrict__ Baug) {
  int z2 = blockIdx.x * 16 + threadIdx.x;  // 256
  int z1 = blockIdx.y * 16 + threadIdx.y;  // 128
  if (z2 >= 128) { Baug[z1 * 256 + z2] = ((z2 - 128) == z1) ? 1.0 : 0.0; return; }
  double acc = 0.0;
#pragma unroll 4
  for (int i = 0; i < NROW; ++i) acc += V[i * NZ + z1] * KZ[i * NZ + z2];
  Baug[z1 * 256 + z2] = acc;
}

// single-block GJ inverse, n <= 66, SPD (HW-proven in R4)
__global__ void k_inv(const double* __restrict__ src, int srcStride,
                      double* __restrict__ dst, int n) {
  __shared__ double A[66 * 67];
  int tx = threadIdx.x, ty = threadIdx.y;
  int tid = ty * 64 + tx;
  for (int idx = tid; idx < n * n; idx += 256)
    A[(idx / n) * 67 + (idx % n)] = src[(idx / n) * srcStride + (idx % n)];
  __syncthreads();
  for (int k = 0; k < n; ++k) {
    double pv = 1.0 / A[k * 67 + k];
    if (ty == 0)
      for (int j = tx; j < n; j += 64) if (j != k) A[k * 67 + j] *= pv;
    __syncthreads();
    for (int ii = ty; ii < n; ii += 4) {
      if (ii == k) continue;
      double fik = A[ii * 67 + k];
      for (int j = tx; j < n; j += 64) if (j != k) A[ii * 67 + j] -= fik * A[k * 67 + j];
      if (tx == 0) A[ii * 67 + k] = -fik * pv;
    }
    if (tid == 0) A[k * 67 + k] = pv;
    __syncthreads();
  }
  for (int idx = tid; idx < n * n; idx += 256)
    dst[idx] = A[(idx / n) * 67 + (idx % n)];
}

__global__ void k_rowscale(const double* __restrict__ Maug, const double* __restrict__ P,
                           double* __restrict__ R, int stride, int nb, int k) {
  int c = nb * (k + 1) + blockIdx.x * 64 + threadIdx.x;
  if (c >= stride) return;
  int rr = blockIdx.y;
  double acc = 0.0;
  for (int t = 0; t < nb; ++t) acc += P[rr * nb + t] * Maug[(nb * k + t) * stride + c];
  R[rr * stride + c] = acc;
}

__global__ void k_update(double* __restrict__ Maug, const double* __restrict__ R,
                         int stride, int n, int nb, int k) {
  int c = nb * (k + 1) + blockIdx.x * 64 + threadIdx.x;
  if (c >= stride) return;
  int i = blockIdx.y;
  int ib = i - nb * k;
  if (ib >= 0 && ib < nb) { Maug[i * stride + c] = R[ib * stride + c]; return; }
  double acc = Maug[i * stride + c];
  for (int t = 0; t < nb; ++t) acc -= Maug[i * stride + nb * k + t] * R[t * stride + c];
  Maug[i * stride + c] = acc;
}

// J[z, t] : input-dim t -> Z^T rhs coefficients
__global__ void k_J(const double* __restrict__ T, const double* __restrict__ V,
                    const float* __restrict__ q, double* __restrict__ J) {
  int t = blockIdx.x * 16 + threadIdx.x;   // 256
  int z = blockIdx.y * 16 + threadIdx.y;   // 128
  double v;
  if (t < 128) {
    v = 2.0 * (double)q[t & 3] * T[t * NZ + z];           // (2 Wq Yf Zg)^T
    if (t >= 124) v += V[(COLS_ + 128 + (t - 124)) * NZ + z];  // ref4 constraint rows
  } else if (t < 192) {
    v = V[(COLS_ + (t - 128)) * NZ + z];                  // u_ini rows
  } else {
    v = V[(COLS_ + 64 + (t - 192)) * NZ + z];             // y_ini rows
  }
  J[z * 256 + t] = v;
}

// F = Binv @ J
__global__ void k_F(const double* __restrict__ Baug, const double* __restrict__ J,
                    double* __restrict__ F) {
  int t = blockIdx.x * 16 + threadIdx.x;   // 256
  int z = blockIdx.y * 16 + threadIdx.y;   // 128
  double acc = 0.0;
#pragma unroll 4
  for (int w = 0; w < 128; ++w) acc += Baug[z * 256 + 128 + w] * J[w * 256 + t];
  F[z * 256 + t] = acc;
}

// Egt[t, c] = sum_z Zg[c,z] * F[z,t]  (f32 map for gemm1)
__global__ void k_Egt2(const double* __restrict__ V, const double* __restrict__ F,
                       float* __restrict__ Egt) {
  int c = blockIdx.x * 16 + threadIdx.x;   // <1536
  int t = blockIdx.y * 16 + threadIdx.y;   // <256
  double acc = 0.0;
  if (c < COLS_) {
#pragma unroll 4
    for (int z = 0; z < 128; ++z) acc += V[c * NZ + z] * F[z * 256 + t];
  }
  Egt[t * EGS + c] = (float)acc;
}

__device__ __forceinline__ float4 loadA4(const float* __restrict__ ref, const float* __restrict__ ui,
                                         const float* __restrict__ yi, int m, int j) {
  if (j < 128) return *(const float4*)&ref[m * 128 + j];
  if (j < 192) return *(const float4*)&ui[m * 64 + (j - 128)];
  return *(const float4*)&yi[m * 64 + (j - 192)];
}

// gemm1: g = Xin(8192x256) @ Egt^T  (R3-proven)
__global__ __launch_bounds__(256) void k_gemm1(const float* __restrict__ ref, const float* __restrict__ ui,
                                               const float* __restrict__ yi, const float* __restrict__ Bm,
                                               float* __restrict__ gout) {
  __shared__ float As[16 * 132];
  __shared__ float Bs[16 * 132];
  const int tid = threadIdx.x;
  const int m0 = blockIdx.y * 128;
  const int n0 = blockIdx.x * 128;
  const int tm = (tid >> 4) * 8;
  const int tn = (tid & 15) * 8;
  const int aRow = tid >> 2;
  const int aQ   = (tid & 3) * 4;
  const int bK   = tid >> 5;
  const int bN   = (tid & 31) * 4;
  float acc[8][8] = {};
  for (int k0 = 0; k0 < 256; k0 += 16) {
    float4 av0 = loadA4(ref, ui, yi, m0 + aRow, k0 + aQ);
    float4 av1 = loadA4(ref, ui, yi, m0 + aRow + 64, k0 + aQ);
    float4 bv0 = *(const float4*)&Bm[(k0 + bK) * EGS + n0 + bN];
    float4 bv1 = *(const float4*)&Bm[(k0 + bK + 8) * EGS + n0 + bN];
    __syncthreads();
    As[(aQ + 0) * 132 + aRow] = av0.x;  As[(aQ + 1) * 132 + aRow] = av0.y;
    As[(aQ + 2) * 132 + aRow] = av0.z;  As[(aQ + 3) * 132 + aRow] = av0.w;
    As[(aQ + 0) * 132 + aRow + 64] = av1.x;  As[(aQ + 1) * 132 + aRow + 64] = av1.y;
    As[(aQ + 2) * 132 + aRow + 64] = av1.z;  As[(aQ + 3) * 132 + aRow + 64] = av1.w;
    *(float4*)&Bs[bK * 132 + bN] = bv0;
    *(float4*)&Bs[(bK + 8) * 132 + bN] = bv1;
    __syncthreads();
#pragma unroll
    for (int kk = 0; kk < 16; ++kk) {
      float4 a0 = *(const float4*)&As[kk * 132 + tm];
      float4 a1 = *(const float4*)&As[kk * 132 + tm + 4];
      float4 b0 = *(const float4*)&Bs[kk * 132 + tn];
      float4 b1 = *(const float4*)&Bs[kk * 132 + tn + 4];
      float av[8] = {a0.x, a0.y, a0.z, a0.w, a1.x, a1.y, a1.z, a1.w};
      float bv[8] = {b0.x, b0.y, b0.z, b0.w, b1.x, b1.y, b1.z, b1.w};
#pragma unroll
      for (int i = 0; i < 8; ++i)
#pragma unroll
        for (int j = 0; j < 8; ++j) acc[i][j] += av[i] * bv[j];
    }
  }
#pragma unroll
  for (int i = 0; i < 8; ++i) {
    int m = m0 + tm + i;
#pragma unroll
    for (int j = 0; j < 8; ++j) {
      int n = n0 + tn + j;
      if (n < COLS_) gout[m * COLS_ + n] = acc[i][j];
    }
  }
}

// gemm2: u = g @ Uf^T, y = g @ Yf^T  (R3-proven)
__global__ __launch_bounds__(256) void k_gemm2(const float* __restrict__ g, const float* __restrict__ ud,
                                               const float* __restrict__ yd,
                                               float* __restrict__ uout, float* __restrict__ yout) {
  __shared__ float Ag[16 * 68];
  __shared__ float Bs[16 * 132];
  const int tid = threadIdx.x;
  const int m0 = blockIdx.y * 64;
  const int n0 = blockIdx.x * 128;
  const float* __restrict__ src = (n0 == 0) ? ud : yd;
  const int tm = (tid >> 4) * 4;
  const int tn = (tid & 15) * 8;
  float acc[4][8] = {};
  for (int c0 = 0; c0 < COLS_; c0 += 16) {
    __syncthreads();
    for (int t = tid; t < 1024; t += 256) {
      int m = t >> 4, kk = t & 15, c = c0 + kk;
      Ag[kk * 68 + m] = (c < COLS_) ? g[(m0 + m) * COLS_ + c] : 0.f;
    }
    for (int t = tid; t < 2048; t += 256) {
      int n = t & 127, kk = t >> 7, c = c0 + kk;
      Bs[kk * 132 + n] = (c < COLS_) ? src[64 + n + 4 * c] : 0.f;
    }
    __syncthreads();
#pragma unroll
    for (int kk = 0; kk < 16; ++kk) {
      float4 a0 = *(const float4*)&Ag[kk * 68 + tm];
      float4 b0 = *(const float4*)&Bs[kk * 132 + tn];
      float4 b1 = *(const float4*)&Bs[kk * 132 + tn + 4];
      float av[4] = {a0.x, a0.y, a0.z, a0.w};
      float bv[8] = {b0.x, b0.y, b0.z, b0.w, b1.x, b1.y, b1.z, b1.w};
#pragma unroll
      for (int i = 0; i < 4; ++i)
#pragma unroll
        for (int j = 0; j < 8; ++j) acc[i][j] += av[i] * bv[j];
    }
  }
  float* __restrict__ dst = (n0 == 0) ? uout : yout;
#pragma unroll
  for (int i = 0; i < 4; ++i)
#pragma unroll
    for (int j = 0; j < 8; ++j)
      dst[(m0 + tm + i) * 128 + tn + j] = acc[i][j];
}

extern "C" void kernel_launch(void* const* d_in, const int* in_sizes, int n_in,
                              void* d_out, int out_size, void* d_ws, size_t ws_size,
                              hipStream_t stream) {
  (void)in_sizes; (void)n_in; (void)out_size; (void)d_ws; (void)ws_size;
  const float* ref   = (const float*)d_in[0];
  const float* u_ini = (const float*)d_in[2];
  const float* y_ini = (const float*)d_in[3];
  const float* ud    = (const float*)d_in[4];
  const float* yd    = (const float*)d_in[5];
  const float* q     = (const float*)d_in[6];
  const float* r     = (const float*)d_in[7];

  float* out  = (float*)d_out;
  float* gout = out;
  float* uout = out + (size_t)NB * COLS_;
  float* yout = uout + (size_t)NB * 128;

  double* Wd = (double*)d_out;
  double* V    = Wd + oV;
  double* Z    = Wd + oZ;
  double* T    = Wd + oT;
  double* KZ   = Wd + oKZ;
  double* Baug = Wd + oBaug;
  double* P    = Wd + oP;
  double* R    = Wd + oR;
  double* J    = Wd + oJ;
  double* F    = Wd + oF;
  float* Egt   = out + fEGT;

  // 1) dominant-128 subspace of K by block power iteration (4 applies)
  k_init<<<dim3(8, 100), dim3(16, 16), 0, stream>>>(V);
  double* a = V; double* b = Z;
  for (int it = 0; it < 4; ++it) {
    k_T<<<dim3(8, 24), dim3(16, 16), 0, stream>>>(a, ud, yd, T);
    k_Zg<<<dim3(8, 91), dim3(16, 16), 0, stream>>>(T, a, ud, yd, q, r, b);
    k_Zl<<<dim3(8, 9), dim3(16, 16), 0, stream>>>(T, b);
    double* t = a; a = b; b = t;
  }
  k_norm<<<128, 256, 0, stream>>>(a);

  // 2) KZ = K @ Znorm ; B = Z^T KZ
  k_T<<<dim3(8, 24), dim3(16, 16), 0, stream>>>(a, ud, yd, T);
  k_Zg<<<dim3(8, 91), dim3(16, 16), 0, stream>>>(T, a, ud, yd, q, r, KZ);
  k_Zl<<<dim3(8, 9), dim3(16, 16), 0, stream>>>(T, KZ);
  k_B<<<dim3(16, 8), dim3(16, 16), 0, stream>>>(a, KZ, Baug);

  // 3) invert B (128x128 SPD) via 2-step blocked GJ
  for (int k = 0; k < 2; ++k) {
    k_inv<<<1, dim3(64, 4), 0, stream>>>(Baug + (size_t)(64 * k) * 256 + 64 * k, 256, P, 64);
    int cs = 64 * (k + 1);
    int gx = (256 - cs + 63) / 64;
    k_rowscale<<<dim3(gx, 64), 64, 0, stream>>>(Baug, P, R, 256, 64, k);
    k_update<<<dim3(gx, 128), 64, 0, stream>>>(Baug, R, 256, 64, 64, k);
  }

  // 4) input->coefficient map F = Binv @ J, then g-map Egt = (Zg F)^T
  k_J<<<dim3(16, 8), dim3(16, 16), 0, stream>>>(T, a, q, J);
  k_F<<<dim3(16, 8), dim3(16, 16), 0, stream>>>(Baug, J, F);
  k_Egt2<<<dim3(96, 16), dim3(16, 16), 0, stream>>>(a, F, Egt);

  // 5) batch: g = Xin @ Egt^T ; u,y from g (reference-identical)
  k_gemm1<<<dim3(12, 64), dim3(256), 0, stream>>>(ref, u_ini, y_ini, Egt, gout);
  k_gemm2<<<dim3(2, 128), dim3(256), 0, stream>>>(gout, ud, yd, uout, yout);
}

// Round 6
// 1028.423 us; speedup vs baseline: 2.3190x; 2.3190x over previous
//
#include <hip/hip_runtime.h>

// Problem constants
#define COLS_ 1453
#define NC 132
#define EGS 1792       // Egt row stride: [g-map 0..1535 | u-map 1536..1663 | y-map 1664..1791]
#define NB 8192

// f64 scratch offsets (doubles) in d_out g-region (dead before gemm1 writes g).
// W rows: 0..63 Up(ud), 64..191 Uf(ud), 192..255 Yp(yd), 256..383 Yf(yd).
#define oGam 0          // Gamma 384x384
#define oC   147456     // c    384x128
#define oV   196608     // v    132x128
#define oGC  213504     // Gamma*c 384x128
#define oCK  262656     // cK   384x128
#define oVK  311808     // vK   132x128
#define oGCK 328704     // Gamma*cK 384x128
#define oB   377856     // [B|I] 128x256
#define oP   410624     // 66x66 pivot
#define oR   414980     // 64x256
#define oJ   431364     // 128x256
#define oF   464132     // 128x256
#define oCE  496900     // 384x256   (end 595204 dbl = 4.76 MB)
// Egt (f32 256x1792 = 1.75 MB) lives in d_ws (R4-proven region).

__device__ __forceinline__ double hash01(unsigned i, unsigned j) {
  unsigned x = i * 0x9E3779B9u ^ (j * 0x85EBCA6Bu + 0xC2B2AE35u);
  x ^= x >> 16; x *= 0x7FEB352Du; x ^= x >> 15; x *= 0x846CA68Bu; x ^= x >> 16;
  return (double)(x & 0xFFFFFF) / 8388608.0 - 1.0;
}

// ---------------- Gram: Gamma = W W^T  (R2-proven structure, +ILP) ----------------
__global__ void k_gram(const float* __restrict__ ud, const float* __restrict__ yd,
                       double* __restrict__ G) {
  __shared__ float sig[12000];
  int tid = threadIdx.y * 16 + threadIdx.x;
  for (int idx = tid; idx < 6000; idx += 256) { sig[idx] = ud[idx]; sig[6000 + idx] = yd[idx]; }
  __syncthreads();
  int i = blockIdx.y * 16 + threadIdx.y;
  int j = blockIdx.x * 16 + threadIdx.x;
  const float* si = &sig[(i < 192) ? i : (6000 + i - 192)];
  const float* sj = &sig[(j < 192) ? j : (6000 + j - 192)];
  double a0 = 0.0, a1 = 0.0, a2 = 0.0, a3 = 0.0;
  for (int c = 0; c < 1452; c += 4) {
    a0 += (double)si[4 * c]      * (double)sj[4 * c];
    a1 += (double)si[4 * c + 4]  * (double)sj[4 * c + 4];
    a2 += (double)si[4 * c + 8]  * (double)sj[4 * c + 8];
    a3 += (double)si[4 * c + 12] * (double)sj[4 * c + 12];
  }
  a0 += (double)si[4 * 1452] * (double)sj[4 * 1452];
  G[i * 384 + j] = (a0 + a1) + (a2 + a3);
}

// ---------------- init c (384x128) and v (132x128) ----------------
__global__ void k_initc(double* __restrict__ c, double* __restrict__ v) {
  int z = blockIdx.x * 16 + threadIdx.x;
  int i = blockIdx.y * 16 + threadIdx.y;
  if (i < 384) c[i * 128 + z] = hash01(i, z);
  else if (i < 516) v[(i - 384) * 128 + z] = hash01(i + 1000, z);
}

// ---------------- GC = Gamma @ c  (384x128) ----------------
__global__ void k_G(const double* __restrict__ Gam, const double* __restrict__ c,
                    double* __restrict__ outp) {
  int z = blockIdx.x * 16 + threadIdx.x;
  int i = blockIdx.y * 16 + threadIdx.y;
  double a0 = 0.0, a1 = 0.0;
  for (int t = 0; t < 384; t += 2) {
    a0 += Gam[i * 384 + t]     * c[t * 128 + z];
    a1 += Gam[i * 384 + t + 1] * c[(t + 1) * 128 + z];
  }
  outp[i * 128 + z] = a0 + a1;
}

// ---------------- K-apply in coordinates: (GC, v) -> (cK, vK) ----------------
__global__ void k_step(const double* __restrict__ GC, const double* __restrict__ v,
                       const float* __restrict__ q, const float* __restrict__ r,
                       double* __restrict__ cK, double* __restrict__ vK) {
  int z = blockIdx.x * 16 + threadIdx.x;
  int i = blockIdx.y * 16 + threadIdx.y;
  if (i >= 516) return;
  if (i < 384) {
    double val;
    if (i < 64)        val = v[i * 128 + z];                                   // A^T v, Up rows
    else if (i < 192)  { int m = i - 64;  val = 2.0 * (double)r[m & 3] * GC[i * 128 + z]; }
    else if (i < 256)  val = v[(64 + i - 192) * 128 + z];                      // A^T v, Yp rows
    else {
      int m = i - 256;
      val = 2.0 * (double)q[m & 3] * GC[i * 128 + z];
      if (m >= 124) val += v[(128 + m - 124) * 128 + z];                        // terminal rows
    }
    cK[i * 128 + z] = val;
  } else {
    int rr = i - 384;
    double val;
    if (rr < 64)       val = GC[rr * 128 + z];                                 // Up g
    else if (rr < 128) val = GC[(192 + rr - 64) * 128 + z];                    // Yp g
    else               val = GC[(380 + rr - 128) * 128 + z];                   // Yf last 4
    vK[rr * 128 + z] = val;
  }
}

// ---------------- normalize columns: scale c, v, GC by 1/||z|| ----------------
__global__ void k_normc(double* __restrict__ c, double* __restrict__ v, double* __restrict__ GC) {
  __shared__ double red[256];
  int z = blockIdx.x, tid = threadIdx.x;
  double s = 0.0;
  for (int i = tid; i < 384; i += 256) s += c[i * 128 + z] * GC[i * 128 + z];
  for (int rr = tid; rr < 132; rr += 256) { double t = v[rr * 128 + z]; s += t * t; }
  red[tid] = s; __syncthreads();
  for (int st = 128; st > 0; st >>= 1) { if (tid < st) red[tid] += red[tid + st]; __syncthreads(); }
  double inv = rsqrt(red[0]);
  for (int i = tid; i < 384; i += 256) { c[i * 128 + z] *= inv; GC[i * 128 + z] *= inv; }
  for (int rr = tid; rr < 132; rr += 256) v[rr * 128 + z] *= inv;
}

// ---------------- Baug = [ c^T GCK + v^T vK | I ]  (128x256) ----------------
__global__ void k_B(const double* __restrict__ c, const double* __restrict__ GCK,
                    const double* __restrict__ v, const double* __restrict__ vK,
                    double* __restrict__ Baug) {
  int z2 = blockIdx.x * 16 + threadIdx.x;
  int z1 = blockIdx.y * 16 + threadIdx.y;
  if (z2 >= 128) { Baug[z1 * 256 + z2] = ((z2 - 128) == z1) ? 1.0 : 0.0; return; }
  double a0 = 0.0, a1 = 0.0;
  for (int i = 0; i < 384; i += 2) {
    a0 += c[i * 128 + z1] * GCK[i * 128 + z2];
    a1 += c[(i + 1) * 128 + z1] * GCK[(i + 1) * 128 + z2];
  }
  for (int rr = 0; rr < 132; ++rr) a0 += v[rr * 128 + z1] * vK[rr * 128 + z2];
  Baug[z1 * 256 + z2] = a0 + a1;
}

// ---------------- single-block GJ inverse (HW-proven) ----------------
__global__ void k_inv(const double* __restrict__ src, int srcStride,
                      double* __restrict__ dst, int n) {
  __shared__ double A[66 * 67];
  int tx = threadIdx.x, ty = threadIdx.y;
  int tid = ty * 64 + tx;
  for (int idx = tid; idx < n * n; idx += 256)
    A[(idx / n) * 67 + (idx % n)] = src[(idx / n) * srcStride + (idx % n)];
  __syncthreads();
  for (int k = 0; k < n; ++k) {
    double pv = 1.0 / A[k * 67 + k];
    if (ty == 0)
      for (int j = tx; j < n; j += 64) if (j != k) A[k * 67 + j] *= pv;
    __syncthreads();
    for (int ii = ty; ii < n; ii += 4) {
      if (ii == k) continue;
      double fik = A[ii * 67 + k];
      for (int j = tx; j < n; j += 64) if (j != k) A[ii * 67 + j] -= fik * A[k * 67 + j];
      if (tx == 0) A[ii * 67 + k] = -fik * pv;
    }
    if (tid == 0) A[k * 67 + k] = pv;
    __syncthreads();
  }
  for (int idx = tid; idx < n * n; idx += 256)
    dst[idx] = A[(idx / n) * 67 + (idx % n)];
}

__global__ void k_rowscale(const double* __restrict__ Maug, const double* __restrict__ P,
                           double* __restrict__ R, int stride, int nb, int k) {
  int c = nb * (k + 1) + blockIdx.x * 64 + threadIdx.x;
  if (c >= stride) return;
  int rr = blockIdx.y;
  double acc = 0.0;
  for (int t = 0; t < nb; ++t) acc += P[rr * nb + t] * Maug[(nb * k + t) * stride + c];
  R[rr * stride + c] = acc;
}

__global__ void k_update(double* __restrict__ Maug, const double* __restrict__ R,
                         int stride, int n, int nb, int k) {
  int c = nb * (k + 1) + blockIdx.x * 64 + threadIdx.x;
  if (c >= stride) return;
  int i = blockIdx.y;
  int ib = i - nb * k;
  if (ib >= 0 && ib < nb) { Maug[i * stride + c] = R[ib * stride + c]; return; }
  double acc = Maug[i * stride + c];
  for (int t = 0; t < nb; ++t) acc -= Maug[i * stride + nb * k + t] * R[t * stride + c];
  Maug[i * stride + c] = acc;
}

// ---------------- J[z,t] = Z^T rhs_t  (from normalized GC, v) ----------------
__global__ void k_J(const double* __restrict__ GC, const double* __restrict__ v,
                    const float* __restrict__ q, double* __restrict__ J) {
  int t = blockIdx.x * 16 + threadIdx.x;
  int z = blockIdx.y * 16 + threadIdx.y;
  double val;
  if (t < 128) {
    val = 2.0 * (double)q[t & 3] * GC[(256 + t) * 128 + z];
    if (t >= 124) val += v[(128 + t - 124) * 128 + z];
  } else if (t < 192) {
    val = v[(t - 128) * 128 + z];
  } else {
    val = v[(64 + t - 192) * 128 + z];
  }
  J[z * 256 + t] = val;
}

// ---------------- F = Binv @ J ----------------
__global__ void k_F(const double* __restrict__ Baug, const double* __restrict__ J,
                    double* __restrict__ F) {
  int t = blockIdx.x * 16 + threadIdx.x;
  int z = blockIdx.y * 16 + threadIdx.y;
  double a0 = 0.0, a1 = 0.0;
  for (int w = 0; w < 128; w += 2) {
    a0 += Baug[z * 256 + 128 + w] * J[w * 256 + t];
    a1 += Baug[z * 256 + 128 + w + 1] * J[(w + 1) * 256 + t];
  }
  F[z * 256 + t] = a0 + a1;
}

// ---------------- CE = c @ F  (384 x 256) ----------------
__global__ void k_CE(const double* __restrict__ c, const double* __restrict__ F,
                     double* __restrict__ CE) {
  int t = blockIdx.x * 16 + threadIdx.x;
  int i = blockIdx.y * 16 + threadIdx.y;
  double a0 = 0.0, a1 = 0.0;
  for (int z = 0; z < 128; z += 2) {
    a0 += c[i * 128 + z] * F[z * 256 + t];
    a1 += c[i * 128 + z + 1] * F[(z + 1) * 256 + t];
  }
  CE[i * 256 + t] = a0 + a1;
}

// ---------------- Egt g-map: Egt[t,c] = sum_i CE[i,t] * W[i,c]  (R3-proven) ----------------
__global__ void k_Egt(const double* __restrict__ CE, const float* __restrict__ ud,
                      const float* __restrict__ yd, float* __restrict__ Egt) {
  __shared__ float sig[12000];
  int tid = threadIdx.y * 16 + threadIdx.x;
  for (int idx = tid; idx < 6000; idx += 256) { sig[idx] = ud[idx]; sig[6000 + idx] = yd[idx]; }
  __syncthreads();
  int c = blockIdx.x * 16 + threadIdx.x;   // < 1536
  int t = blockIdx.y * 16 + threadIdx.y;   // < 256
  double a0 = 0.0, a1 = 0.0;
  if (c < COLS_) {
    for (int i = 0; i < 384; i += 2) {
      int off0 = (i < 192) ? i : (6000 + i - 192);
      int off1 = (i + 1 < 192) ? (i + 1) : (6000 + i + 1 - 192);
      a0 += CE[i * 256 + t] * (double)sig[off0 + 4 * c];
      a1 += CE[(i + 1) * 256 + t] * (double)sig[off1 + 4 * c];
    }
  }
  Egt[t * EGS + c] = (float)(a0 + a1);
}

// ---------------- Egt u/y maps: cols 1536..1791 ----------------
__global__ void k_Euy(const double* __restrict__ GC, const double* __restrict__ F,
                      float* __restrict__ Egt) {
  int n = blockIdx.x * 16 + threadIdx.x;   // 256
  int t = blockIdx.y * 16 + threadIdx.y;   // 256
  int row = (n < 128) ? (64 + n) : (128 + n);   // Uf rows 64..191 ; Yf rows 256..383
  double a0 = 0.0, a1 = 0.0;
  for (int z = 0; z < 128; z += 2) {
    a0 += GC[row * 128 + z] * F[z * 256 + t];
    a1 += GC[row * 128 + z + 1] * F[(z + 1) * 256 + t];
  }
  Egt[t * EGS + 1536 + n] = (float)(a0 + a1);
}

// ---------------- A-operand loader ----------------
__device__ __forceinline__ float4 loadA4(const float* __restrict__ ref, const float* __restrict__ ui,
                                         const float* __restrict__ yi, int m, int j) {
  if (j < 128) return *(const float4*)&ref[m * 128 + j];
  if (j < 192) return *(const float4*)&ui[m * 64 + (j - 128)];
  return *(const float4*)&yi[m * 64 + (j - 192)];
}

// ---------------- gemm1: [g|u|y] = Xin(8192x256) @ Egt^T(256x1792) ----------------
// B-fragments read as two 64-col half-tiles at lane-stride 16B (2-way LDS aliasing = free).
__global__ __launch_bounds__(256) void k_gemm1(const float* __restrict__ ref, const float* __restrict__ ui,
                                               const float* __restrict__ yi, const float* __restrict__ Bm,
                                               float* __restrict__ gout, float* __restrict__ uout,
                                               float* __restrict__ yout) {
  __shared__ float As[16 * 132];
  __shared__ float Bs[16 * 132];
  const int tid = threadIdx.x;
  const int m0 = blockIdx.y * 128;
  const int n0 = blockIdx.x * 128;
  const int tm  = (tid >> 4) * 8;
  const int tn0 = (tid & 15) * 4;
  const int aRow = tid >> 2;
  const int aQ   = (tid & 3) * 4;
  const int bK   = tid >> 5;
  const int bN   = (tid & 31) * 4;
  float acc[8][8] = {};
  for (int k0 = 0; k0 < 256; k0 += 16) {
    float4 av0 = loadA4(ref, ui, yi, m0 + aRow, k0 + aQ);
    float4 av1 = loadA4(ref, ui, yi, m0 + aRow + 64, k0 + aQ);
    float4 bv0 = *(const float4*)&Bm[(k0 + bK) * EGS + n0 + bN];
    float4 bv1 = *(const float4*)&Bm[(k0 + bK + 8) * EGS + n0 + bN];
    __syncthreads();
    As[(aQ + 0) * 132 + aRow] = av0.x;  As[(aQ + 1) * 132 + aRow] = av0.y;
    As[(aQ + 2) * 132 + aRow] = av0.z;  As[(aQ + 3) * 132 + aRow] = av0.w;
    As[(aQ + 0) * 132 + aRow + 64] = av1.x;  As[(aQ + 1) * 132 + aRow + 64] = av1.y;
    As[(aQ + 2) * 132 + aRow + 64] = av1.z;  As[(aQ + 3) * 132 + aRow + 64] = av1.w;
    *(float4*)&Bs[bK * 132 + bN] = bv0;
    *(float4*)&Bs[(bK + 8) * 132 + bN] = bv1;
    __syncthreads();
#pragma unroll
    for (int kk = 0; kk < 16; ++kk) {
      float4 a0 = *(const float4*)&As[kk * 132 + tm];
      float4 a1 = *(const float4*)&As[kk * 132 + tm + 4];
      float4 b0 = *(const float4*)&Bs[kk * 132 + tn0];
      float4 b1 = *(const float4*)&Bs[kk * 132 + 64 + tn0];
      float av[8] = {a0.x, a0.y, a0.z, a0.w, a1.x, a1.y, a1.z, a1.w};
      float bv[8] = {b0.x, b0.y, b0.z, b0.w, b1.x, b1.y, b1.z, b1.w};
#pragma unroll
      for (int i = 0; i < 8; ++i)
#pragma unroll
        for (int j = 0; j < 8; ++j) acc[i][j] += av[i] * bv[j];
    }
  }
#pragma unroll
  for (int i = 0; i < 8; ++i) {
    int m = m0 + tm + i;
#pragma unroll
    for (int j = 0; j < 8; ++j) {
      int n = n0 + ((j < 4) ? (tn0 + j) : (64 + tn0 + (j - 4)));
      float vv = acc[i][j];
      if (n < COLS_)       gout[(size_t)m * COLS_ + n] = vv;
      else if (n >= 1664)  yout[m * 128 + (n - 1664)] = vv;
      else if (n >= 1536)  uout[m * 128 + (n - 1536)] = vv;
    }
  }
}

extern "C" void kernel_launch(void* const* d_in, const int* in_sizes, int n_in,
                              void* d_out, int out_size, void* d_ws, size_t ws_size,
                              hipStream_t stream) {
  (void)in_sizes; (void)n_in; (void)out_size; (void)ws_size;
  const float* ref   = (const float*)d_in[0];
  const float* u_ini = (const float*)d_in[2];
  const float* y_ini = (const float*)d_in[3];
  const float* ud    = (const float*)d_in[4];
  const float* yd    = (const float*)d_in[5];
  const float* q     = (const float*)d_in[6];
  const float* r     = (const float*)d_in[7];

  float* out  = (float*)d_out;
  float* gout = out;
  float* uout = out + (size_t)NB * COLS_;
  float* yout = uout + (size_t)NB * 128;

  double* Wd  = (double*)d_out;
  double* Gam = Wd + oGam;
  double* c   = Wd + oC;
  double* v   = Wd + oV;
  double* GC  = Wd + oGC;
  double* cK  = Wd + oCK;
  double* vK  = Wd + oVK;
  double* GCK = Wd + oGCK;
  double* Ba  = Wd + oB;
  double* P   = Wd + oP;
  double* R   = Wd + oR;
  double* J   = Wd + oJ;
  double* F   = Wd + oF;
  double* CE  = Wd + oCE;
  float* Egt  = (float*)d_ws;    // 256x1792 f32 (R4-proven d_ws region)

  // 1) Gram matrix (the only 1453-deep f64 kernel)
  k_gram<<<dim3(24, 24), dim3(16, 16), 0, stream>>>(ud, yd, Gam);

  // 2) block power iteration for the dominant-128 subspace, in 384+132 coordinates
  k_initc<<<dim3(8, 33), dim3(16, 16), 0, stream>>>(c, v);
  double* ca = c;  double* va = v;
  double* cb = cK; double* vb = vK;
  for (int it = 0; it < 4; ++it) {
    k_G<<<dim3(8, 24), dim3(16, 16), 0, stream>>>(Gam, ca, GC);
    k_step<<<dim3(8, 33), dim3(16, 16), 0, stream>>>(GC, va, q, r, cb, vb);
    double* t1 = ca; ca = cb; cb = t1;
    double* t2 = va; va = vb; vb = t2;
  }
  // ca/va hold the iterate (== c/v buffers after 4 swaps)

  // 3) normalize; KZ in coordinates; B = Z^T K Z
  k_G<<<dim3(8, 24), dim3(16, 16), 0, stream>>>(Gam, ca, GC);
  k_normc<<<128, 256, 0, stream>>>(ca, va, GC);
  k_step<<<dim3(8, 33), dim3(16, 16), 0, stream>>>(GC, va, q, r, cb, vb);
  k_G<<<dim3(8, 24), dim3(16, 16), 0, stream>>>(Gam, cb, GCK);
  k_B<<<dim3(16, 8), dim3(16, 16), 0, stream>>>(ca, GCK, va, vb, Ba);

  // 4) invert B (128x128 SPD), 2-step blocked GJ
  for (int k = 0; k < 2; ++k) {
    k_inv<<<1, dim3(64, 4), 0, stream>>>(Ba + (size_t)(64 * k) * 256 + 64 * k, 256, P, 64);
    int cs = 64 * (k + 1);
    int gx = (256 - cs + 63) / 64;
    k_rowscale<<<dim3(gx, 64), 64, 0, stream>>>(Ba, P, R, 256, 64, k);
    k_update<<<dim3(gx, 128), 64, 0, stream>>>(Ba, R, 256, 64, 64, k);
  }

  // 5) input->coefficient map and the three output maps
  k_J<<<dim3(16, 8), dim3(16, 16), 0, stream>>>(GC, va, q, J);
  k_F<<<dim3(16, 8), dim3(16, 16), 0, stream>>>(Ba, J, F);
  k_CE<<<dim3(16, 24), dim3(16, 16), 0, stream>>>(ca, F, CE);
  k_Egt<<<dim3(96, 16), dim3(16, 16), 0, stream>>>(CE, ud, yd, Egt);
  k_Euy<<<dim3(16, 16), dim3(16, 16), 0, stream>>>(GC, F, Egt);

  // 6) one batch GEMM produces g, u, y
  k_gemm1<<<dim3(14, 64), dim3(256), 0, stream>>>(ref, u_ini, y_ini, Egt, gout, uout, yout);
}